// Round 7
// baseline (539.254 us; speedup 1.0000x reference)
//
#include <hip/hip_runtime.h>
#include <math.h>

// 16-qubit statevector, 512 batch. Inter-pass psi FP16 (half2/amp), 128 MiB.
// This round (codegen only, math bit-identical):
//  * All packed-FMA accumulator chains use TIED asm constraints ("+v",
//    v_pk_fma_f32 %0,%1,%2,%0) so regalloc cannot insert v_mov copies —
//    p4's VALUBusy 65% vs ~1160 counted essential VALU/wave implied ~1700
//    hidden overhead instructions.
//  * Lane-xor 1/2/3 cross-lane moves via DPP quad_perm (1-cy VALU) instead
//    of ds_swizzle (DS pipe, ~40+cy latency): wsum steps 1-2, p4 Xd, p5 X01.
//  * Class sums via tied v_pk_add_f32.
// Structure (passes, tiles, swizzles, barriers) identical to round-6.

#define NT 256
#define ACCS 40
#define BSZQ 512

typedef float v2f __attribute__((ext_vector_type(2)));
typedef __fp16 h2t __attribute__((ext_vector_type(2)));

__device__ __forceinline__ v2f mk2(float a, float b){ v2f r; r.x = a; r.y = b; return r; }

// Compile-time ordering fence for intra-wave LDS exchange (no HW cost).
__device__ __forceinline__ void wave_fence(){
  asm volatile("" ::: "memory");
  __builtin_amdgcn_wave_barrier();
  asm volatile("" ::: "memory");
}

__device__ __forceinline__ unsigned int f2h(v2f a){
  h2t h = __builtin_amdgcn_cvt_pkrtz(a.x, a.y);
  return *(unsigned int*)&h;
}
__device__ __forceinline__ v2f h2f(unsigned int u){
  h2t h = *(h2t*)&u;
  return mk2((float)h.x, (float)h.y);
}

// ---- packed fp32 primitives (VOP3P), accumulators TIED to kill movs ----
__device__ __forceinline__ v2f pk_mul(v2f a, v2f b){
  v2f d; asm("v_pk_mul_f32 %0, %1, %2" : "=v"(d) : "v"(a), "v"(b)); return d;
}
__device__ __forceinline__ void pk_fma_acc(v2f& c, v2f a, v2f b){
  asm("v_pk_fma_f32 %0, %1, %2, %0" : "+v"(c) : "v"(a), "v"(b));
}
// a consumed SWAPPED: lo result uses a.hi, hi result uses a.lo.
__device__ __forceinline__ void pk_fma_sw_acc(v2f& c, v2f a, v2f b){
  asm("v_pk_fma_f32 %0, %1, %2, %0 op_sel:[1,0,0] op_sel_hi:[0,1,1]"
      : "+v"(c) : "v"(a), "v"(b));
}
__device__ __forceinline__ void pk_add_acc(v2f& c, v2f a){
  asm("v_pk_add_f32 %0, %1, %0" : "+v"(c) : "v"(a));
}

struct C2 { float r, i; };
struct G1Q { C2 a, b, c, d; };

__device__ __forceinline__ C2 cmul(C2 x, C2 y){ return C2{ x.r*y.r - x.i*y.i, x.r*y.i + x.i*y.r }; }
__device__ __forceinline__ C2 cadd(C2 x, C2 y){ return C2{ x.r + y.r, x.i + y.i }; }
__device__ __forceinline__ G1Q mkRX(float th){
  float cc = cosf(0.5f*th), ss = sinf(0.5f*th);
  return G1Q{ C2{cc,0.f}, C2{0.f,-ss}, C2{0.f,-ss}, C2{cc,0.f} };
}
__device__ __forceinline__ G1Q mkRY(float th){
  float cc = cosf(0.5f*th), ss = sinf(0.5f*th);
  return G1Q{ C2{cc,0.f}, C2{-ss,0.f}, C2{ss,0.f}, C2{cc,0.f} };
}
__device__ __forceinline__ G1Q gmul(G1Q A, G1Q B){
  return G1Q{ cadd(cmul(A.a,B.a), cmul(A.b,B.c)),
              cadd(cmul(A.a,B.b), cmul(A.b,B.d)),
              cadd(cmul(A.c,B.a), cmul(A.d,B.c)),
              cadd(cmul(A.c,B.b), cmul(A.d,B.d)) };
}

struct PG1Q { v2f aR, aI, bR, bI, cR, cI, dR, dI; };
__device__ __forceinline__ PG1Q loadPG(const float* __restrict__ gt, int i){
  const float4* p = (const float4*)(gt + i*8);
  float4 u = p[0], w = p[1];
  PG1Q g;
  g.aR = mk2(u.x, u.x); g.aI = mk2(-u.y, u.y);
  g.bR = mk2(u.z, u.z); g.bI = mk2(-u.w, u.w);
  g.cR = mk2(w.x, w.x); g.cI = mk2(-w.y, w.y);
  g.dR = mk2(w.z, w.z); g.dI = mk2(-w.w, w.w);
  return g;
}

__device__ __forceinline__ int swzA(int l){ return (l & 0xFF0) | (((l>>4) ^ l) & 15); }
__device__ __forceinline__ int swzB(int l){ return (l & 0xFF0) | (((l>>8) ^ l) & 15); }

// Lane xor via ds_swizzle (masks >=4) or DPP quad_perm (masks 1,2,3: VALU).
template<int M>
__device__ __forceinline__ float swzx(float x){
  return __int_as_float(__builtin_amdgcn_ds_swizzle(__float_as_int(x), (M<<10)|0x1F));
}
// DPP quad_perm ctrl: xor1=[1,0,3,2]=0xB1, xor2=[2,3,0,1]=0x4E, xor3=[3,2,1,0]=0x1B
template<int C>
__device__ __forceinline__ float dppx(float x){
  return __int_as_float(__builtin_amdgcn_mov_dpp(__float_as_int(x), C, 0xF, 0xF, true));
}
// Full-wave sum: xor1,xor2 via DPP (VALU), xor4,8,16 via ds_swizzle, + readlanes.
__device__ __forceinline__ float wsum(float x){
  x += dppx<0xB1>(x);
  x += dppx<0x4E>(x);
  x += swzx<4>(x);
  x += swzx<8>(x);
  x += swzx<16>(x);
  return __int_as_float(__builtin_amdgcn_readlane(__float_as_int(x), 0)) +
         __int_as_float(__builtin_amdgcn_readlane(__float_as_int(x), 32));
}

__device__ __forceinline__ void greg16p(v2f* v, const PG1Q g, const int q){
  const int bq = 1<<q;
  #pragma unroll
  for (int r=0;r<16;r++){
    if (r & bq) continue;
    v2f a0 = v[r], a1 = v[r|bq];
    v2f t0 = pk_mul(a0, g.aR);
    pk_fma_sw_acc(t0, a0, g.aI);
    pk_fma_acc   (t0, a1, g.bR);
    pk_fma_sw_acc(t0, a1, g.bI);
    v2f t1 = pk_mul(a0, g.cR);
    pk_fma_sw_acc(t1, a0, g.cI);
    pk_fma_acc   (t1, a1, g.dR);
    pk_fma_sw_acc(t1, a1, g.dI);
    v[r] = t0; v[r|bq] = t1;
  }
}
__device__ __forceinline__ void creg16(v2f* v, const int qc, const int qt){
  #pragma unroll
  for (int r=0;r<16;r++){
    if ((r & (1<<qc)) && !(r & (1<<qt))){
      v2f tmp = v[r]; v[r] = v[r|(1<<qt)]; v[r|(1<<qt)] = tmp;
    }
  }
}
__device__ __forceinline__ float xdot16p(const v2f* v, const int m){
  v2f s = pk_mul(v[0], v[m]);
  #pragma unroll
  for (int r=1;r<16;r++) pk_fma_acc(s, v[r], v[r^m]);
  return s.x + s.y;
}

// ---------------- P0: bake the 14 composed gates (1 thread) ----------------
__global__ void qs_prep(const float* __restrict__ ra, const float* __restrict__ trx,
                        const float* __restrict__ tryv, float* __restrict__ gt){
  if (threadIdx.x != 0) return;
  float trx0 = trx[0];
  G1Q RX0 = mkRX(trx0);
  G1Q g[14];
  g[0]  = gmul(RX0, gmul(mkRY(ra[19]), mkRX(ra[3])));   // p1 alpha q0 (w15)
  g[1]  = mkRX(trx0 + ra[6]);                           // p1 alpha q1
  g[2]  = mkRX(trx0 + ra[9]);                           // p1 alpha q2
  g[3]  = mkRX(trx0 + ra[12]);                          // p1 alpha q3
  g[4]  = mkRX(trx0 + ra[15]);                          // p1 beta q0
  g[5]  = mkRX(trx0 + ra[18]);                          // p1 beta q1
  g[6]  = RX0;                                          // shared
  g[7]  = gmul(RX0, mkRY(ra[4]));                       // p2 A q3 (w4)
  g[8]  = mkRY(ra[1]);                                  // p2 A q2 (w5 RY)
  g[9]  = gmul(RX0, mkRY(ra[7]));                       // p2 B q0 (w3)
  g[10] = gmul(RX0, mkRY(ra[10]));                      // p2 B q1 (w2)
  g[11] = gmul(RX0, mkRY(ra[13]));                      // p2 B q2 (w1)
  g[12] = gmul(RX0, gmul(mkRY(ra[16]), mkRX(ra[0])));   // p2 B q3 (w0)
  g[13] = gmul(mkRX(trx[1]), mkRY(tryv[0]));            // U for p4/p5
  for (int i=0;i<14;i++){
    gt[i*8+0]=g[i].a.r; gt[i*8+1]=g[i].a.i;
    gt[i*8+2]=g[i].b.r; gt[i*8+3]=g[i].b.i;
    gt[i*8+4]=g[i].c.r; gt[i*8+5]=g[i].c.i;
    gt[i*8+6]=g[i].d.r; gt[i*8+7]=g[i].d.i;
  }
}

// ---------------- P1 (L tile): input->complex, random-layer L gates + RX0 ----------------
// LDS transpose is intra-wave (partners share tid>>4) -> NO __syncthreads.
__global__ __launch_bounds__(NT) void qs_p1(const float* __restrict__ x, const float* __restrict__ gt,
                                            unsigned int* __restrict__ psi, float* __restrict__ acc){
  __shared__ __align__(16) v2f s[4096];
  int b = blockIdx.x >> 4, t = blockIdx.x & 15;
  int tid = threadIdx.x;
  if (t == 0 && tid < ACCS) acc[b*ACCS + tid] = 0.f;
  v2f v[16];
  // phase alpha: regs = bits 0..3, threads = bits 4..11
  const float4* xb = (const float4*)(x + (size_t)b*65536 + t*4096 + tid*16);
  #pragma unroll
  for (int q=0;q<4;q++){
    float4 f = xb[q];
    v[4*q+0] = mk2(f.x, 0.f);
    v[4*q+1] = mk2(f.y, 0.f);
    v[4*q+2] = mk2(f.z, 0.f);
    v[4*q+3] = mk2(f.w, 0.f);
  }
  greg16p(v, loadPG(gt,0), 0);   // w15
  greg16p(v, loadPG(gt,1), 1);   // w14
  greg16p(v, loadPG(gt,2), 2);   // w13
  greg16p(v, loadPG(gt,3), 3);   // w12
  #pragma unroll
  for (int j=0;j<16;j++) s[swzA(j | (tid<<4))] = v[j];
  wave_fence();
  // phase beta: regs = bits 4..7; tid: b0..3 = bits 0..3, b4..7 = bits 8..11
  #pragma unroll
  for (int r=0;r<16;r++) v[r] = s[swzA((tid&15) | (r<<4) | ((tid>>4)<<8))];
  creg16(v, 1, 0);                       // C(w10->w11)
  creg16(v, 2, 1);                       // C(w9->w10)
  creg16(v, 3, 2);                       // C(w8->w9)
  {                                      // C(w7->w8): ctrl bit8 = tid bit4, tgt bit7 = r3
    bool c8 = (tid & 16);
    #pragma unroll
    for (int r=0;r<8;r++){
      v2f lo = v[r], hi = v[r|8];
      v[r]   = c8 ? hi : lo;
      v[r|8] = c8 ? lo : hi;
    }
  }
  greg16p(v, loadPG(gt,4), 0);   // w11
  greg16p(v, loadPG(gt,5), 1);   // w10
  PG1Q PG6 = loadPG(gt,6);
  greg16p(v, PG6, 2);            // w9
  greg16p(v, PG6, 3);            // w8
  unsigned int* pbL = psi + (size_t)b*65536 + t*4096;
  #pragma unroll
  for (int r=0;r<16;r++) pbL[(tid&15) | (r<<4) | ((tid>>4)<<8)] = f2h(v[r]);
}

// ---------------- P2 (H tile): random-layer H gates + RX0 on wires 0..7 ----------------
// Transpose partners vary tid>>4 (inter-wave) -> keep the single barrier.
__global__ __launch_bounds__(NT) void qs_p2(unsigned int* __restrict__ psi, const float* __restrict__ gt){
  __shared__ __align__(16) v2f s[4096];
  int b = blockIdx.x >> 4, t = blockIdx.x & 15;
  int tid = threadIdx.x;
  v2f v[16];
  unsigned int* pb = psi + (size_t)b*65536;
  // phase A: regs = g8..11; tid: b0..3 = g0..3, b4..7 = g12..15
  #pragma unroll
  for (int r=0;r<16;r++)
    v[r] = h2f(pb[(tid&15) | (t<<4) | (r<<8) | ((tid>>4)<<12)]);
  greg16p(v, loadPG(gt,7), 3);   // w4
  greg16p(v, loadPG(gt,8), 2);   // w5 (RY part)
  creg16(v, 1, 0);               // C(w6->w7)
  creg16(v, 2, 1);               // C(w5->w6)
  PG1Q PG6 = loadPG(gt,6);
  greg16p(v, PG6, 2);            // w5
  greg16p(v, PG6, 1);            // w6
  greg16p(v, PG6, 0);            // w7
  #pragma unroll
  for (int r=0;r<16;r++) s[swzA((tid&15) | (r<<4) | ((tid>>4)<<8))] = v[r];
  __syncthreads();
  // phase B: regs = g12..15; tid: b0..3 = g0..3, b4..7 = g8..11
  #pragma unroll
  for (int r=0;r<16;r++) v[r] = s[swzA((tid&15) | ((tid>>4)<<4) | (r<<8))];
  greg16p(v, loadPG(gt,9), 0);    // w3
  greg16p(v, loadPG(gt,10), 1);   // w2
  greg16p(v, loadPG(gt,11), 2);   // w1
  greg16p(v, loadPG(gt,12), 3);   // w0
  #pragma unroll
  for (int r=0;r<16;r++)
    pb[(tid&15) | (t<<4) | ((tid>>4)<<8) | (r<<12)] = f2h(v[r]);
}

// ---------------- P4 (H tile on y-frame, T folded into load/store addr) ----------------
// Phases A (y0..3) -> C (y12..15) -> B (y8..11). A->C transpose intra-wave
// (wave_fence); RDC->WRC self-region (wave_fence); C->B inter-wave (1 barrier).
__global__ __launch_bounds__(NT) void qs_p4(unsigned int* __restrict__ psi, const float* __restrict__ gt,
                                            float* __restrict__ acc){
  __shared__ __align__(16) v2f s[4096];
  int b = blockIdx.x >> 4, t = blockIdx.x & 15;
  int tid = threadIdx.x;
  PG1Q U = loadPG(gt, 13);
  unsigned int* pb = psi + (size_t)b*65536;
  v2f v[16];
  // ---- phase A: regs y0..3; tid: b0..3 = y12..15, b4..7 = y8..11 ----
  {
    int Y = (tid>>4) | ((tid&15)<<4);          // y8..15
    int XH = Y ^ (Y>>1);                       // x8..15
    int x7 = ((t>>3) ^ Y) & 1;                 // t3 ^ y8
    int runbase = (XH<<8) | (x7<<7) | (((t ^ (t>>1)) & 7) << 4);
    const uint4* rp = (const uint4*)(pb + runbase);
    v2f tmp[16];
    #pragma unroll
    for (int q=0;q<4;q++){
      uint4 u = rp[q];
      tmp[4*q+0] = h2f(u.x);
      tmp[4*q+1] = h2f(u.y);
      tmp[4*q+2] = h2f(u.z);
      tmp[4*q+3] = h2f(u.w);
    }
    // v[j] = tmp[alpha], j bitk = parity(alpha>>k) (^15 if t0)
    if (t & 1){
      v[15]=tmp[0];  v[14]=tmp[1];  v[12]=tmp[2];  v[13]=tmp[3];
      v[ 8]=tmp[4];  v[ 9]=tmp[5];  v[11]=tmp[6];  v[10]=tmp[7];
      v[ 0]=tmp[8];  v[ 1]=tmp[9];  v[ 3]=tmp[10]; v[ 2]=tmp[11];
      v[ 7]=tmp[12]; v[ 6]=tmp[13]; v[ 4]=tmp[14]; v[ 5]=tmp[15];
    } else {
      v[ 0]=tmp[0];  v[ 1]=tmp[1];  v[ 3]=tmp[2];  v[ 2]=tmp[3];
      v[ 7]=tmp[4];  v[ 6]=tmp[5];  v[ 4]=tmp[6];  v[ 5]=tmp[7];
      v[15]=tmp[8];  v[14]=tmp[9];  v[12]=tmp[10]; v[13]=tmp[11];
      v[ 8]=tmp[12]; v[ 9]=tmp[13]; v[11]=tmp[14]; v[10]=tmp[15];
    }
    // K = C(w15->w0): ctrl y0 (reg bit0), tgt y15 (lane bit3) -> lane-xor swap
    #pragma unroll
    for (int r=1;r<16;r+=2){
      v[r].x = swzx<8>(v[r].x);
      v[r].y = swzx<8>(v[r].y);
    }
    greg16p(v, U, 0); greg16p(v, U, 1); greg16p(v, U, 2); greg16p(v, U, 3); // w15,w14,w13,w12
    #pragma unroll
    for (int j=0;j<16;j++)
      s[swzB(j | ((tid>>4)<<4) | ((tid&15)<<8))] = v[j];
  }
  wave_fence();   // A->C transpose is intra-wave (partners share tid>>4)
  float Xa, Xb, Xc, Xd;
  // ---- phase C: regs y12..15; tid: b0..3 = y0..3, b4..7 = y8..11 ----
  {
    #pragma unroll
    for (int r=0;r<16;r++)
      v[r] = s[swzB((tid&15) | ((tid>>4)<<4) | (r<<8))];
    greg16p(v, U, 0); greg16p(v, U, 1); greg16p(v, U, 2); greg16p(v, U, 3); // w3,w2,w1,w0
    creg16(v, 3, 2);  // chain1 C(w0->w1)
    creg16(v, 2, 1);  // C(w1->w2)
    creg16(v, 1, 0);  // C(w2->w3)
    Xa = xdot16p(v, 8);   // X_w0 (y15)
    Xb = xdot16p(v, 4);   // X_w1 (y14)
    Xc = xdot16p(v, 2);   // X_w2 (y13)
    v2f XdP = mk2(0.f, 0.f);  // <X_w0 X_w15> = y15 (reg) x y0 (lane bit0) -> DPP xor1
    #pragma unroll
    for (int r=0;r<16;r++)
      pk_fma_acc(XdP, v[r], mk2(dppx<0xB1>(v[r^8].x), dppx<0xB1>(v[r^8].y)));
    Xd = XdP.x + XdP.y;
    wave_fence();   // RDC -> WRC: each thread overwrites only its own region {a,b,*}
    #pragma unroll
    for (int r=0;r<16;r++)
      s[swzB((tid&15) | ((tid>>4)<<4) | (r<<8))] = v[r];
  }
  __syncthreads();  // C->B transpose is inter-wave: the one required barrier
  // ---- phase B: regs y8..11; tid: b0..3 = y0..3, b4..7 = y12..15 ----
  float Xe, Xf, Xg, Xh;
  {
    #pragma unroll
    for (int r=0;r<16;r++)
      v[r] = s[swzB((tid&15) | (r<<4) | ((tid>>4)<<8))];
    greg16p(v, U, 0); greg16p(v, U, 1); greg16p(v, U, 2); greg16p(v, U, 3); // w7,w6,w5,w4
    {                                  // C(w3->w4): ctrl y12 = tid bit4, tgt y11 = r3
      bool c12 = (tid & 16);
      #pragma unroll
      for (int r=0;r<8;r++){
        v2f lo = v[r], hi = v[r|8];
        v[r]   = c12 ? hi : lo;
        v[r|8] = c12 ? lo : hi;
      }
    }
    creg16(v, 3, 2);  // C(w4->w5)
    creg16(v, 2, 1);  // C(w5->w6)
    creg16(v, 1, 0);  // C(w6->w7)
    v2f XeP = mk2(0.f, 0.f);   // X_w3 (y12 = lane bit4)
    #pragma unroll
    for (int r=0;r<16;r++)
      pk_fma_acc(XeP, v[r], mk2(swzx<16>(v[r].x), swzx<16>(v[r].y)));
    Xe = XeP.x + XeP.y;
    Xf = xdot16p(v, 8);   // X_w4
    Xg = xdot16p(v, 4);   // X_w5
    Xh = xdot16p(v, 2);   // X_w6
    // store, T folded: g(base|r<<8) = g(base) ^ ((r<<8)^(r<<7))
    int Bs = (tid&15) | (t<<4) | ((tid>>4)<<12);
    int Cs = Bs ^ (Bs>>1);
    #pragma unroll
    for (int r=0;r<16;r++)
      pb[Cs ^ ((r<<8) ^ (r<<7))] = f2h(v[r]);
  }
  float vals[8] = {Xa, Xb, Xc, Xe, Xf, Xg, Xh, Xd};
  #pragma unroll
  for (int i=0;i<8;i++) vals[i] = wsum(vals[i]);
  if ((tid & 63) == 0){
    float* A = acc + b*ACCS;
    #pragma unroll
    for (int i=0;i<7;i++) atomicAdd(A+25+i, vals[i]);
    atomicAdd(A+32, vals[7]);
  }
}

// ---------------- P5 (L tile, read-only, single-phase, no LDS) ----------------
__global__ __launch_bounds__(NT) void qs_p5(const unsigned int* __restrict__ psi, const float* __restrict__ gt,
                                            float* __restrict__ acc){
  int b = blockIdx.x >> 4, t = blockIdx.x & 15;
  int tid = threadIdx.x;
  PG1Q U = loadPG(gt, 13);
  const unsigned int* pb = psi + (size_t)b*65536;
  v2f v[16];
  // T-unfold gather, strength-reduced: addr(r) = g(Bv) ^ ((r<<4)^(r<<3))
  int Bv = (t<<12) | ((tid>>4)<<8) | (tid&15);
  int Cg = Bv ^ (Bv>>1);
  #pragma unroll
  for (int r=0;r<16;r++)
    v[r] = h2f(pb[Cg ^ ((r<<4) ^ (r<<3))]);
  greg16p(v, U, 0); greg16p(v, U, 1); greg16p(v, U, 2); greg16p(v, U, 3); // w11..w8
  v2f z2 = mk2(0.f, 0.f);
  v2f totP=z2, S4P=z2, S5P=z2, S6P=z2, S7P=z2;
  #pragma unroll
  for (int r=0;r<16;r++){
    v2f sq = pk_mul(v[r], v[r]);
    pk_add_acc(totP, sq);
    if (__popc(r)&1)    pk_add_acc(S4P, sq);
    if (__popc(r>>1)&1) pk_add_acc(S5P, sq);
    if (__popc(r>>2)&1) pk_add_acc(S6P, sq);
    if (__popc(r>>3)&1) pk_add_acc(S7P, sq);
  }
  float totA = totP.x + totP.y;
  float S4l = S4P.x + S4P.y, S5l = S5P.x + S5P.y;
  float S6l = S6P.x + S6P.y, S7l = S7P.x + S7P.y;
  float S4h = totA - S4l;
  float S0 = (__popc(tid & 0x1F)&1) ? S4h : S4l;   // parity(ul0..8)
  float S1 = (__popc(tid & 0x1E)&1) ? S4h : S4l;   // parity(ul1..8)
  float S2 = (__popc(tid & 0x1C)&1) ? S4h : S4l;   // parity(ul2..8)
  float S3 = (__popc(tid & 0x18)&1) ? S4h : S4l;   // parity(ul3..8)
  bool u8 = (tid & 16);
  float S4 = u8 ? S4h : S4l;                       // parity(ul4..8)
  float S5 = u8 ? totA - S5l : S5l;
  float S6 = u8 ? totA - S6l : S6l;
  float S7 = u8 ? totA - S7l : S7l;
  float S8 = u8 ? totA : 0.f;
  float K9  = (tid & 32) ? totA : 0.f;
  float K10 = (tid & 64) ? totA : 0.f;
  float K11 = (tid & 128)? totA : 0.f;
  float X45 = xdot16p(v,3), X56 = xdot16p(v,6), X67 = xdot16p(v,12);
  v2f X01P=z2, X12P=z2, X23P=z2, X34P=z2, X78P=z2;
  #pragma unroll
  for (int r=0;r<16;r++){
    float vx = v[r].x, vy = v[r].y;
    pk_fma_acc(X01P, v[r], mk2(dppx<0x1B>(vx), dppx<0x1B>(vy)));          // lane xor3 (ul0,ul1)
    pk_fma_acc(X12P, v[r], mk2(swzx<6>(vx),  swzx<6>(vy)));               // lane xor6 (ul1,ul2)
    pk_fma_acc(X23P, v[r], mk2(swzx<12>(vx), swzx<12>(vy)));              // lane xor12 (ul2,ul3)
    pk_fma_acc(X34P, v[r], mk2(swzx<8>(v[r^1].x), swzx<8>(v[r^1].y)));    // ul3 x ul4
    pk_fma_acc(X78P, v[r], mk2(swzx<16>(v[r^8].x), swzx<16>(v[r^8].y)));  // ul7 x ul8
  }
  float X01 = X01P.x + X01P.y, X12 = X12P.x + X12P.y, X23 = X23P.x + X23P.y;
  float X34 = X34P.x + X34P.y, X78 = X78P.x + X78P.y;
  float vals[21] = {totA, S0,S1,S2,S3,S4,S5,S6,S7,S8, K9,K10,K11,
                    X01,X12,X23,X34,X45,X56,X67,X78};
  #pragma unroll
  for (int i=0;i<21;i++) vals[i] = wsum(vals[i]);
  if ((tid & 63) == 0){
    float* A = acc + b*ACCS;
    atomicAdd(A+0, vals[0]);
    #pragma unroll
    for (int p=0;p<12;p++) atomicAdd(A+1+p, vals[1+p]);
    if (t&1) atomicAdd(A+13, vals[0]);
    if (t&2) atomicAdd(A+14, vals[0]);
    if (t&4) atomicAdd(A+15, vals[0]);
    float zz = vals[0] - 2.f*vals[1];
    if (t&8) zz = -zz;
    atomicAdd(A+16, zz);
    #pragma unroll
    for (int j=0;j<8;j++) atomicAdd(A+17+j, vals[13+j]);
  }
}

// ---------------- Tail (unchanged, verified) ----------------
__global__ __launch_bounds__(256) void qs_tail(const float* __restrict__ acc, const float* __restrict__ tryv,
    const float* __restrict__ w1, const float* __restrict__ b1,
    const float* __restrict__ w2, const float* __restrict__ b2,
    const float* __restrict__ g1, const float* __restrict__ be1,
    const float* __restrict__ g2, const float* __restrict__ be2,
    const float* __restrict__ wh, const float* __restrict__ bh,
    float* __restrict__ out){
  int b = blockIdx.x * 256 + threadIdx.x;
  if (b >= BSZQ) return;
  const float* A = acc + b*ACCS;
  float tot = A[0];
  float inv = 1.f / tot;
  float Z[16], X[16];
  Z[0] = A[16] * inv;
  Z[1] = 1.f - 2.f*A[15]*inv;
  Z[2] = 1.f - 2.f*A[14]*inv;
  Z[3] = 1.f - 2.f*A[13]*inv;
  #pragma unroll
  for (int w=4; w<15; w++) Z[w] = 1.f - 2.f*A[1 + (15-w)]*inv;
  Z[15] = 1.f - 2.f*A[1]*inv;
  #pragma unroll
  for (int w=0; w<7; w++) X[w] = A[25+w]*inv;
  #pragma unroll
  for (int w=7; w<15; w++) X[w] = A[16 + (15-w)]*inv;
  X[15] = A[32]*inv;
  float th = tryv[1];
  float ct = cosf(th), st = sinf(th);
  float M4[16];
  #pragma unroll
  for (int w=0; w<16; w++) M4[w] = ct*Z[w] - st*X[w];
  float mu = 0.f;
  #pragma unroll
  for (int w=0; w<16; w++) mu += Z[w];
  mu *= (1.f/16.f);
  float var = 0.f;
  #pragma unroll
  for (int w=0; w<16; w++){ float d = Z[w]-mu; var += d*d; }
  var *= (1.f/16.f);
  float rs = rsqrtf(var + 1e-5f);
  float xln[16];
  #pragma unroll
  for (int w=0; w<16; w++) xln[w] = (Z[w]-mu)*rs*g1[16+w] + be1[16+w];
  float h[64];
  for (int j=0;j<64;j++){
    float sacc = b1[64 + j];
    #pragma unroll
    for (int w=0; w<16; w++) sacc += M4[w] * w1[1024 + j*16 + w];
    h[j] = fmaxf(sacc, 0.f);
  }
  float y[16];
  for (int w=0; w<16; w++){
    float sacc = b2[16 + w];
    #pragma unroll
    for (int j=0;j<64;j++) sacc += h[j] * w2[1024 + w*64 + j];
    y[w] = xln[w] + sacc;
  }
  mu = 0.f;
  #pragma unroll
  for (int w=0; w<16; w++) mu += y[w];
  mu *= (1.f/16.f);
  var = 0.f;
  #pragma unroll
  for (int w=0; w<16; w++){ float d = y[w]-mu; var += d*d; }
  var *= (1.f/16.f);
  rs = rsqrtf(var + 1e-5f);
  float o = bh[0];
  #pragma unroll
  for (int w=0; w<16; w++) o += ((y[w]-mu)*rs*g2[16+w] + be2[16+w]) * wh[w];
  out[b] = o;
}

extern "C" void kernel_launch(void* const* d_in, const int* in_sizes, int n_in,
                              void* d_out, int out_size, void* d_ws, size_t ws_size,
                              hipStream_t stream) {
  const float* states = (const float*)d_in[0];
  const float* ra     = (const float*)d_in[1];
  const float* trx    = (const float*)d_in[2];
  const float* tryv   = (const float*)d_in[3];
  const float* w1     = (const float*)d_in[4];
  const float* b1     = (const float*)d_in[5];
  const float* w2     = (const float*)d_in[6];
  const float* b2     = (const float*)d_in[7];
  const float* g1     = (const float*)d_in[8];
  const float* be1    = (const float*)d_in[9];
  const float* g2     = (const float*)d_in[10];
  const float* be2    = (const float*)d_in[11];
  const float* wh     = (const float*)d_in[12];
  const float* bh     = (const float*)d_in[13];
  float* out = (float*)d_out;

  unsigned int* psi = (unsigned int*)d_ws;                                 // 128 MiB (fp16 amps)
  float* acc  = (float*)((char*)d_ws + (size_t)BSZQ*65536*sizeof(float2)); // keep old offset (512 x 40)
  float* gt = out;  // gate table in d_out scratch; qs_tail overwrites it all

  dim3 g(BSZQ*16);
  qs_prep<<<1, 64, 0, stream>>>(ra, trx, tryv, gt);
  qs_p1<<<g, NT, 0, stream>>>(states, gt, psi, acc);
  qs_p2<<<g, NT, 0, stream>>>(psi, gt);
  qs_p4<<<g, NT, 0, stream>>>(psi, gt, acc);
  qs_p5<<<g, NT, 0, stream>>>(psi, gt, acc);
  qs_tail<<<2, 256, 0, stream>>>(acc, tryv, w1, b1, w2, b2, g1, be1, g2, be2, wh, bh, out);
}

// Round 8
// 535.774 us; speedup vs baseline: 1.0065x; 1.0065x over previous
//
#include <hip/hip_runtime.h>
#include <math.h>

// 16-qubit statevector, 512 batch. Inter-pass psi FP16 (half2/amp), 128 MiB.
// This round: LDS halved 32KB -> 16KB per block via TWO-ROUND transposes
// (occupancy cap was LDS: 128 B/thread * 2048 thr/CU = 256 KB > 160 KB ->
// only 5 blocks/CU resident). Each 16<->16 exchange splits on one address
// bit so round-0 writes fully serve round-0 reads. p1 / p4-A->C remain
// intra-wave (wave_fence only; validated by round-6 pass); p2 / p4-C->B use
// 3-4 barriers (measured ~free). Uniform bank swizzle low4 ^= (i>>4)^(i>>8).
// Plus stage-major batched wave reductions (wsumB<N>): 21-way ILP instead of
// 21 serial 5-deep swizzle chains. Math bit-identical to round 6/7.

#define NT 256
#define ACCS 40
#define BSZQ 512

typedef float v2f __attribute__((ext_vector_type(2)));
typedef __fp16 h2t __attribute__((ext_vector_type(2)));

__device__ __forceinline__ v2f mk2(float a, float b){ v2f r; r.x = a; r.y = b; return r; }

__device__ __forceinline__ void wave_fence(){
  asm volatile("" ::: "memory");
  __builtin_amdgcn_wave_barrier();
  asm volatile("" ::: "memory");
}

__device__ __forceinline__ unsigned int f2h(v2f a){
  h2t h = __builtin_amdgcn_cvt_pkrtz(a.x, a.y);
  return *(unsigned int*)&h;
}
__device__ __forceinline__ v2f h2f(unsigned int u){
  h2t h = *(h2t*)&u;
  return mk2((float)h.x, (float)h.y);
}

// ---- packed fp32 primitives (VOP3P), tied accumulators ----
__device__ __forceinline__ v2f pk_mul(v2f a, v2f b){
  v2f d; asm("v_pk_mul_f32 %0, %1, %2" : "=v"(d) : "v"(a), "v"(b)); return d;
}
__device__ __forceinline__ void pk_fma_acc(v2f& c, v2f a, v2f b){
  asm("v_pk_fma_f32 %0, %1, %2, %0" : "+v"(c) : "v"(a), "v"(b));
}
__device__ __forceinline__ void pk_fma_sw_acc(v2f& c, v2f a, v2f b){
  asm("v_pk_fma_f32 %0, %1, %2, %0 op_sel:[1,0,0] op_sel_hi:[0,1,1]"
      : "+v"(c) : "v"(a), "v"(b));
}
__device__ __forceinline__ void pk_add_acc(v2f& c, v2f a){
  asm("v_pk_add_f32 %0, %1, %0" : "+v"(c) : "v"(a));
}

struct C2 { float r, i; };
struct G1Q { C2 a, b, c, d; };

__device__ __forceinline__ C2 cmul(C2 x, C2 y){ return C2{ x.r*y.r - x.i*y.i, x.r*y.i + x.i*y.r }; }
__device__ __forceinline__ C2 cadd(C2 x, C2 y){ return C2{ x.r + y.r, x.i + y.i }; }
__device__ __forceinline__ G1Q mkRX(float th){
  float cc = cosf(0.5f*th), ss = sinf(0.5f*th);
  return G1Q{ C2{cc,0.f}, C2{0.f,-ss}, C2{0.f,-ss}, C2{cc,0.f} };
}
__device__ __forceinline__ G1Q mkRY(float th){
  float cc = cosf(0.5f*th), ss = sinf(0.5f*th);
  return G1Q{ C2{cc,0.f}, C2{-ss,0.f}, C2{ss,0.f}, C2{cc,0.f} };
}
__device__ __forceinline__ G1Q gmul(G1Q A, G1Q B){
  return G1Q{ cadd(cmul(A.a,B.a), cmul(A.b,B.c)),
              cadd(cmul(A.a,B.b), cmul(A.b,B.d)),
              cadd(cmul(A.c,B.a), cmul(A.d,B.c)),
              cadd(cmul(A.c,B.b), cmul(A.d,B.d)) };
}

struct PG1Q { v2f aR, aI, bR, bI, cR, cI, dR, dI; };
__device__ __forceinline__ PG1Q loadPG(const float* __restrict__ gt, int i){
  const float4* p = (const float4*)(gt + i*8);
  float4 u = p[0], w = p[1];
  PG1Q g;
  g.aR = mk2(u.x, u.x); g.aI = mk2(-u.y, u.y);
  g.bR = mk2(u.z, u.z); g.bI = mk2(-u.w, u.w);
  g.cR = mk2(w.x, w.x); g.cI = mk2(-w.y, w.y);
  g.dR = mk2(w.z, w.z); g.dI = mk2(-w.w, w.w);
  return g;
}

// Compact 16 KB transpose-buffer swizzle: fold high address bits into low4.
__device__ __forceinline__ int SW(int i){ return (i & ~15) | ((i ^ (i>>4) ^ (i>>8)) & 15); }

template<int M>
__device__ __forceinline__ float swzx(float x){
  return __int_as_float(__builtin_amdgcn_ds_swizzle(__float_as_int(x), (M<<10)|0x1F));
}
template<int C>
__device__ __forceinline__ float dppx(float x){
  return __int_as_float(__builtin_amdgcn_mov_dpp(__float_as_int(x), C, 0xF, 0xF, true));
}
// Stage-major batched full-wave sums: N-way ILP per butterfly stage.
template<int N>
__device__ __forceinline__ void wsumB(float* x){
  #pragma unroll
  for (int i=0;i<N;i++) x[i] += dppx<0xB1>(x[i]);
  #pragma unroll
  for (int i=0;i<N;i++) x[i] += dppx<0x4E>(x[i]);
  #pragma unroll
  for (int i=0;i<N;i++) x[i] += swzx<4>(x[i]);
  #pragma unroll
  for (int i=0;i<N;i++) x[i] += swzx<8>(x[i]);
  #pragma unroll
  for (int i=0;i<N;i++) x[i] += swzx<16>(x[i]);
  #pragma unroll
  for (int i=0;i<N;i++)
    x[i] = __int_as_float(__builtin_amdgcn_readlane(__float_as_int(x[i]), 0)) +
           __int_as_float(__builtin_amdgcn_readlane(__float_as_int(x[i]), 32));
}

__device__ __forceinline__ void greg16p(v2f* v, const PG1Q g, const int q){
  const int bq = 1<<q;
  #pragma unroll
  for (int r=0;r<16;r++){
    if (r & bq) continue;
    v2f a0 = v[r], a1 = v[r|bq];
    v2f t0 = pk_mul(a0, g.aR);
    pk_fma_sw_acc(t0, a0, g.aI);
    pk_fma_acc   (t0, a1, g.bR);
    pk_fma_sw_acc(t0, a1, g.bI);
    v2f t1 = pk_mul(a0, g.cR);
    pk_fma_sw_acc(t1, a0, g.cI);
    pk_fma_acc   (t1, a1, g.dR);
    pk_fma_sw_acc(t1, a1, g.dI);
    v[r] = t0; v[r|bq] = t1;
  }
}
__device__ __forceinline__ void creg16(v2f* v, const int qc, const int qt){
  #pragma unroll
  for (int r=0;r<16;r++){
    if ((r & (1<<qc)) && !(r & (1<<qt))){
      v2f tmp = v[r]; v[r] = v[r|(1<<qt)]; v[r|(1<<qt)] = tmp;
    }
  }
}
__device__ __forceinline__ float xdot16p(const v2f* v, const int m){
  v2f s = pk_mul(v[0], v[m]);
  #pragma unroll
  for (int r=1;r<16;r++) pk_fma_acc(s, v[r], v[r^m]);
  return s.x + s.y;
}

// ---------------- P0: bake the 14 composed gates (1 thread) ----------------
__global__ void qs_prep(const float* __restrict__ ra, const float* __restrict__ trx,
                        const float* __restrict__ tryv, float* __restrict__ gt){
  if (threadIdx.x != 0) return;
  float trx0 = trx[0];
  G1Q RX0 = mkRX(trx0);
  G1Q g[14];
  g[0]  = gmul(RX0, gmul(mkRY(ra[19]), mkRX(ra[3])));   // p1 alpha q0 (w15)
  g[1]  = mkRX(trx0 + ra[6]);                           // p1 alpha q1
  g[2]  = mkRX(trx0 + ra[9]);                           // p1 alpha q2
  g[3]  = mkRX(trx0 + ra[12]);                          // p1 alpha q3
  g[4]  = mkRX(trx0 + ra[15]);                          // p1 beta q0
  g[5]  = mkRX(trx0 + ra[18]);                          // p1 beta q1
  g[6]  = RX0;                                          // shared
  g[7]  = gmul(RX0, mkRY(ra[4]));                       // p2 A q3 (w4)
  g[8]  = mkRY(ra[1]);                                  // p2 A q2 (w5 RY)
  g[9]  = gmul(RX0, mkRY(ra[7]));                       // p2 B q0 (w3)
  g[10] = gmul(RX0, mkRY(ra[10]));                      // p2 B q1 (w2)
  g[11] = gmul(RX0, mkRY(ra[13]));                      // p2 B q2 (w1)
  g[12] = gmul(RX0, gmul(mkRY(ra[16]), mkRX(ra[0])));   // p2 B q3 (w0)
  g[13] = gmul(mkRX(trx[1]), mkRY(tryv[0]));            // U for p4/p5
  for (int i=0;i<14;i++){
    gt[i*8+0]=g[i].a.r; gt[i*8+1]=g[i].a.i;
    gt[i*8+2]=g[i].b.r; gt[i*8+3]=g[i].b.i;
    gt[i*8+4]=g[i].c.r; gt[i*8+5]=g[i].c.i;
    gt[i*8+6]=g[i].d.r; gt[i*8+7]=g[i].d.i;
  }
}

// ---------------- P1 (L tile): input->complex, random-layer L gates + RX0 ----------------
// Two-round 16KB transpose, intra-wave (group = tid>>4, fences only).
// Exchange: reader (a=tid&15,g) reg r <- writer (tid&15=r,g) reg j=a.
// idx = (j&7) | (a_w<<3) | (g<<7); rounds split on j>>3.
__global__ __launch_bounds__(NT) void qs_p1(const float* __restrict__ x, const float* __restrict__ gt,
                                            unsigned int* __restrict__ psi, float* __restrict__ acc){
  __shared__ __align__(16) v2f s[2048];
  int b = blockIdx.x >> 4, t = blockIdx.x & 15;
  int tid = threadIdx.x;
  if (t == 0 && tid < ACCS) acc[b*ACCS + tid] = 0.f;
  v2f v[16];
  const float4* xb = (const float4*)(x + (size_t)b*65536 + t*4096 + tid*16);
  #pragma unroll
  for (int q=0;q<4;q++){
    float4 f = xb[q];
    v[4*q+0] = mk2(f.x, 0.f);
    v[4*q+1] = mk2(f.y, 0.f);
    v[4*q+2] = mk2(f.z, 0.f);
    v[4*q+3] = mk2(f.w, 0.f);
  }
  greg16p(v, loadPG(gt,0), 0);   // w15
  greg16p(v, loadPG(gt,1), 1);   // w14
  greg16p(v, loadPG(gt,2), 2);   // w13
  greg16p(v, loadPG(gt,3), 3);   // w12
  // ---- two-round transpose (alpha -> beta frame) ----
  {
    int wbase = ((tid&15)<<3) | ((tid>>4)<<7);
    int rbase = (tid&7) | ((tid>>4)<<7);
    v2f tmp[8];
    #pragma unroll
    for (int j=0;j<8;j++) s[SW(j | wbase)] = v[j];          // round 0: all write j<8
    wave_fence();
    if (!(tid & 8)){                                        // readers a<8: read all 16
      #pragma unroll
      for (int r=0;r<8;r++)  v[r]     = s[SW(rbase | (r<<3))];
      #pragma unroll
      for (int r=8;r<16;r++) tmp[r-8] = s[SW(rbase | (r<<3))];
    }
    wave_fence();
    #pragma unroll
    for (int j=8;j<16;j++) s[SW((j&7) | wbase)] = v[j];     // round 1: all write j>=8
    wave_fence();
    if (tid & 8){                                           // readers a>=8: read all 16
      #pragma unroll
      for (int r=0;r<16;r++) v[r] = s[SW(rbase | (r<<3))];
    } else {
      #pragma unroll
      for (int r=8;r<16;r++) v[r] = tmp[r-8];
    }
  }
  // phase beta
  creg16(v, 1, 0);                       // C(w10->w11)
  creg16(v, 2, 1);                       // C(w9->w10)
  creg16(v, 3, 2);                       // C(w8->w9)
  {                                      // C(w7->w8)
    bool c8 = (tid & 16);
    #pragma unroll
    for (int r=0;r<8;r++){
      v2f lo = v[r], hi = v[r|8];
      v[r]   = c8 ? hi : lo;
      v[r|8] = c8 ? lo : hi;
    }
  }
  greg16p(v, loadPG(gt,4), 0);   // w11
  greg16p(v, loadPG(gt,5), 1);   // w10
  PG1Q PG6 = loadPG(gt,6);
  greg16p(v, PG6, 2);            // w9
  greg16p(v, PG6, 3);            // w8
  unsigned int* pbL = psi + (size_t)b*65536 + t*4096;
  #pragma unroll
  for (int r=0;r<16;r++) pbL[(tid&15) | (r<<4) | ((tid>>4)<<8)] = f2h(v[r]);
}

// ---------------- P2 (H tile): random-layer H gates + RX0 on wires 0..7 ----------------
// Two-round 16KB transpose, inter-wave (3 barriers).
// Exchange: reader (a, x=tid>>4) reg r <- writer (a, tid>>4=r) reg x.
// idx = ((tid>>4)&7) | (reg<<3) | (a<<7); rounds split on writer tid>>4 >= 8.
__global__ __launch_bounds__(NT) void qs_p2(unsigned int* __restrict__ psi, const float* __restrict__ gt){
  __shared__ __align__(16) v2f s[2048];
  int b = blockIdx.x >> 4, t = blockIdx.x & 15;
  int tid = threadIdx.x;
  v2f v[16];
  unsigned int* pb = psi + (size_t)b*65536;
  #pragma unroll
  for (int r=0;r<16;r++)
    v[r] = h2f(pb[(tid&15) | (t<<4) | (r<<8) | ((tid>>4)<<12)]);
  greg16p(v, loadPG(gt,7), 3);   // w4
  greg16p(v, loadPG(gt,8), 2);   // w5 (RY part)
  creg16(v, 1, 0);               // C(w6->w7)
  creg16(v, 2, 1);               // C(w5->w6)
  PG1Q PG6 = loadPG(gt,6);
  greg16p(v, PG6, 2);            // w5
  greg16p(v, PG6, 1);            // w6
  greg16p(v, PG6, 0);            // w7
  // ---- two-round transpose ----
  {
    int wbase = ((tid>>4)&7) | ((tid&15)<<7);
    int rbase = ((tid>>4)<<3) | ((tid&15)<<7);
    v2f tmp[8];
    if (tid < 128){                                         // round 0 writers
      #pragma unroll
      for (int rr=0;rr<16;rr++) s[SW(wbase | (rr<<3))] = v[rr];
    }
    __syncthreads();
    #pragma unroll
    for (int r=0;r<8;r++) tmp[r] = s[SW(rbase | (r&7))];    // all read r<8
    __syncthreads();
    if (tid >= 128){                                        // round 1 writers
      #pragma unroll
      for (int rr=0;rr<16;rr++) s[SW(wbase | (rr<<3))] = v[rr];
    }
    __syncthreads();
    #pragma unroll
    for (int r=8;r<16;r++) v[r] = s[SW(rbase | (r&7))];     // all read r>=8
    #pragma unroll
    for (int r=0;r<8;r++) v[r] = tmp[r];
  }
  greg16p(v, loadPG(gt,9), 0);    // w3
  greg16p(v, loadPG(gt,10), 1);   // w2
  greg16p(v, loadPG(gt,11), 2);   // w1
  greg16p(v, loadPG(gt,12), 3);   // w0
  #pragma unroll
  for (int r=0;r<16;r++)
    pb[(tid&15) | (t<<4) | ((tid>>4)<<8) | (r<<12)] = f2h(v[r]);
}

// ---------------- P4 (H tile on y-frame, T folded into load/store addr) ----------------
// A->C: two-round intra-wave (idx = (tid&7... q=(tid&15)&7 | (j<<3) | (g<<7),
//   split on writer tid&15 >= 8); C->B: two-round inter-wave (same shape as p2).
__global__ __launch_bounds__(NT) void qs_p4(unsigned int* __restrict__ psi, const float* __restrict__ gt,
                                            float* __restrict__ acc){
  __shared__ __align__(16) v2f s[2048];
  int b = blockIdx.x >> 4, t = blockIdx.x & 15;
  int tid = threadIdx.x;
  PG1Q U = loadPG(gt, 13);
  unsigned int* pb = psi + (size_t)b*65536;
  v2f v[16];
  // ---- phase A: regs y0..3; tid: b0..3 = y12..15, b4..7 = y8..11 ----
  {
    int Y = (tid>>4) | ((tid&15)<<4);          // y8..15
    int XH = Y ^ (Y>>1);                       // x8..15
    int x7 = ((t>>3) ^ Y) & 1;                 // t3 ^ y8
    int runbase = (XH<<8) | (x7<<7) | (((t ^ (t>>1)) & 7) << 4);
    const uint4* rp = (const uint4*)(pb + runbase);
    v2f tmp[16];
    #pragma unroll
    for (int q=0;q<4;q++){
      uint4 u = rp[q];
      tmp[4*q+0] = h2f(u.x);
      tmp[4*q+1] = h2f(u.y);
      tmp[4*q+2] = h2f(u.z);
      tmp[4*q+3] = h2f(u.w);
    }
    if (t & 1){
      v[15]=tmp[0];  v[14]=tmp[1];  v[12]=tmp[2];  v[13]=tmp[3];
      v[ 8]=tmp[4];  v[ 9]=tmp[5];  v[11]=tmp[6];  v[10]=tmp[7];
      v[ 0]=tmp[8];  v[ 1]=tmp[9];  v[ 3]=tmp[10]; v[ 2]=tmp[11];
      v[ 7]=tmp[12]; v[ 6]=tmp[13]; v[ 4]=tmp[14]; v[ 5]=tmp[15];
    } else {
      v[ 0]=tmp[0];  v[ 1]=tmp[1];  v[ 3]=tmp[2];  v[ 2]=tmp[3];
      v[ 7]=tmp[4];  v[ 6]=tmp[5];  v[ 4]=tmp[6];  v[ 5]=tmp[7];
      v[15]=tmp[8];  v[14]=tmp[9];  v[12]=tmp[10]; v[13]=tmp[11];
      v[ 8]=tmp[12]; v[ 9]=tmp[13]; v[11]=tmp[14]; v[10]=tmp[15];
    }
    // K = C(w15->w0): ctrl y0 (reg bit0), tgt y15 (lane bit3) -> lane-xor swap
    #pragma unroll
    for (int r=1;r<16;r+=2){
      v[r].x = swzx<8>(v[r].x);
      v[r].y = swzx<8>(v[r].y);
    }
    greg16p(v, U, 0); greg16p(v, U, 1); greg16p(v, U, 2); greg16p(v, U, 3); // w15,w14,w13,w12
  }
  // ---- A->C two-round transpose (intra-wave, group = tid>>4) ----
  // reader (a=tid&15,g) reg r <- writer (tid&15=r,g) reg j=a.
  {
    int wbase = (tid&7) | ((tid>>4)<<7);
    int rbase = ((tid&15)<<3) | ((tid>>4)<<7);
    v2f tmp[8];
    if (!(tid & 8)){                                        // round 0 writers (tid&15 < 8)
      #pragma unroll
      for (int j=0;j<16;j++) s[SW(wbase | (j<<3))] = v[j];
    }
    wave_fence();
    #pragma unroll
    for (int r=0;r<8;r++) tmp[r] = s[SW((r&7) | rbase)];    // all read r<8
    wave_fence();
    if (tid & 8){                                           // round 1 writers
      #pragma unroll
      for (int j=0;j<16;j++) s[SW(wbase | (j<<3))] = v[j];
    }
    wave_fence();
    #pragma unroll
    for (int r=8;r<16;r++) v[r] = s[SW((r&7) | rbase)];     // all read r>=8
    #pragma unroll
    for (int r=0;r<8;r++) v[r] = tmp[r];
  }
  float Xa, Xb, Xc, Xd;
  // ---- phase C: regs y12..15; tid: b0..3 = y0..3, b4..7 = y8..11 ----
  {
    greg16p(v, U, 0); greg16p(v, U, 1); greg16p(v, U, 2); greg16p(v, U, 3); // w3,w2,w1,w0
    creg16(v, 3, 2);  // chain1 C(w0->w1)
    creg16(v, 2, 1);  // C(w1->w2)
    creg16(v, 1, 0);  // C(w2->w3)
    Xa = xdot16p(v, 8);   // X_w0 (y15)
    Xb = xdot16p(v, 4);   // X_w1 (y14)
    Xc = xdot16p(v, 2);   // X_w2 (y13)
    v2f XdP = mk2(0.f, 0.f);  // <X_w0 X_w15>: reg^8 x lane-xor1 (DPP)
    #pragma unroll
    for (int r=0;r<16;r++)
      pk_fma_acc(XdP, v[r], mk2(dppx<0xB1>(v[r^8].x), dppx<0xB1>(v[r^8].y)));
    Xd = XdP.x + XdP.y;
  }
  // ---- C->B two-round transpose (inter-wave; pre-barrier drains A->C reads) ----
  // reader (a, y=tid>>4) reg r <- writer (a, tid>>4=r) reg y.
  {
    int wbase = ((tid>>4)&7) | ((tid&15)<<7);
    int rbase = ((tid>>4)<<3) | ((tid&15)<<7);
    v2f tmp[8];
    __syncthreads();                                        // all waves past A->C reads
    if (tid < 128){
      #pragma unroll
      for (int rr=0;rr<16;rr++) s[SW(wbase | (rr<<3))] = v[rr];
    }
    __syncthreads();
    #pragma unroll
    for (int r=0;r<8;r++) tmp[r] = s[SW(rbase | (r&7))];
    __syncthreads();
    if (tid >= 128){
      #pragma unroll
      for (int rr=0;rr<16;rr++) s[SW(wbase | (rr<<3))] = v[rr];
    }
    __syncthreads();
    #pragma unroll
    for (int r=8;r<16;r++) v[r] = s[SW(rbase | (r&7))];
    #pragma unroll
    for (int r=0;r<8;r++) v[r] = tmp[r];
  }
  // ---- phase B: regs y8..11; tid: b0..3 = y0..3, b4..7 = y12..15 ----
  float Xe, Xf, Xg, Xh;
  {
    greg16p(v, U, 0); greg16p(v, U, 1); greg16p(v, U, 2); greg16p(v, U, 3); // w7,w6,w5,w4
    {                                  // C(w3->w4): ctrl y12 = tid bit4, tgt y11 = r3
      bool c12 = (tid & 16);
      #pragma unroll
      for (int r=0;r<8;r++){
        v2f lo = v[r], hi = v[r|8];
        v[r]   = c12 ? hi : lo;
        v[r|8] = c12 ? lo : hi;
      }
    }
    creg16(v, 3, 2);  // C(w4->w5)
    creg16(v, 2, 1);  // C(w5->w6)
    creg16(v, 1, 0);  // C(w6->w7)
    v2f XeP = mk2(0.f, 0.f);   // X_w3 (y12 = lane bit4)
    #pragma unroll
    for (int r=0;r<16;r++)
      pk_fma_acc(XeP, v[r], mk2(swzx<16>(v[r].x), swzx<16>(v[r].y)));
    Xe = XeP.x + XeP.y;
    Xf = xdot16p(v, 8);   // X_w4
    Xg = xdot16p(v, 4);   // X_w5
    Xh = xdot16p(v, 2);   // X_w6
    int Bs = (tid&15) | (t<<4) | ((tid>>4)<<12);
    int Cs = Bs ^ (Bs>>1);
    #pragma unroll
    for (int r=0;r<16;r++)
      pb[Cs ^ ((r<<8) ^ (r<<7))] = f2h(v[r]);
  }
  float vals[8] = {Xa, Xb, Xc, Xe, Xf, Xg, Xh, Xd};
  wsumB<8>(vals);
  if ((tid & 63) == 0){
    float* A = acc + b*ACCS;
    #pragma unroll
    for (int i=0;i<7;i++) atomicAdd(A+25+i, vals[i]);
    atomicAdd(A+32, vals[7]);
  }
}

// ---------------- P5 (L tile, read-only, single-phase, no LDS) ----------------
__global__ __launch_bounds__(NT) void qs_p5(const unsigned int* __restrict__ psi, const float* __restrict__ gt,
                                            float* __restrict__ acc){
  int b = blockIdx.x >> 4, t = blockIdx.x & 15;
  int tid = threadIdx.x;
  PG1Q U = loadPG(gt, 13);
  const unsigned int* pb = psi + (size_t)b*65536;
  v2f v[16];
  int Bv = (t<<12) | ((tid>>4)<<8) | (tid&15);
  int Cg = Bv ^ (Bv>>1);
  #pragma unroll
  for (int r=0;r<16;r++)
    v[r] = h2f(pb[Cg ^ ((r<<4) ^ (r<<3))]);
  greg16p(v, U, 0); greg16p(v, U, 1); greg16p(v, U, 2); greg16p(v, U, 3); // w11..w8
  v2f z2 = mk2(0.f, 0.f);
  v2f totP=z2, S4P=z2, S5P=z2, S6P=z2, S7P=z2;
  #pragma unroll
  for (int r=0;r<16;r++){
    v2f sq = pk_mul(v[r], v[r]);
    pk_add_acc(totP, sq);
    if (__popc(r)&1)    pk_add_acc(S4P, sq);
    if (__popc(r>>1)&1) pk_add_acc(S5P, sq);
    if (__popc(r>>2)&1) pk_add_acc(S6P, sq);
    if (__popc(r>>3)&1) pk_add_acc(S7P, sq);
  }
  float totA = totP.x + totP.y;
  float S4l = S4P.x + S4P.y, S5l = S5P.x + S5P.y;
  float S6l = S6P.x + S6P.y, S7l = S7P.x + S7P.y;
  float S4h = totA - S4l;
  float S0 = (__popc(tid & 0x1F)&1) ? S4h : S4l;   // parity(ul0..8)
  float S1 = (__popc(tid & 0x1E)&1) ? S4h : S4l;   // parity(ul1..8)
  float S2 = (__popc(tid & 0x1C)&1) ? S4h : S4l;   // parity(ul2..8)
  float S3 = (__popc(tid & 0x18)&1) ? S4h : S4l;   // parity(ul3..8)
  bool u8 = (tid & 16);
  float S4 = u8 ? S4h : S4l;                       // parity(ul4..8)
  float S5 = u8 ? totA - S5l : S5l;
  float S6 = u8 ? totA - S6l : S6l;
  float S7 = u8 ? totA - S7l : S7l;
  float S8 = u8 ? totA : 0.f;
  float K9  = (tid & 32) ? totA : 0.f;
  float K10 = (tid & 64) ? totA : 0.f;
  float K11 = (tid & 128)? totA : 0.f;
  float X45 = xdot16p(v,3), X56 = xdot16p(v,6), X67 = xdot16p(v,12);
  v2f X01P=z2, X12P=z2, X23P=z2, X34P=z2, X78P=z2;
  #pragma unroll
  for (int r=0;r<16;r++){
    float vx = v[r].x, vy = v[r].y;
    pk_fma_acc(X01P, v[r], mk2(dppx<0x1B>(vx), dppx<0x1B>(vy)));          // lane xor3
    pk_fma_acc(X12P, v[r], mk2(swzx<6>(vx),  swzx<6>(vy)));               // lane xor6
    pk_fma_acc(X23P, v[r], mk2(swzx<12>(vx), swzx<12>(vy)));              // lane xor12
    pk_fma_acc(X34P, v[r], mk2(swzx<8>(v[r^1].x), swzx<8>(v[r^1].y)));    // ul3 x ul4
    pk_fma_acc(X78P, v[r], mk2(swzx<16>(v[r^8].x), swzx<16>(v[r^8].y)));  // ul7 x ul8
  }
  float X01 = X01P.x + X01P.y, X12 = X12P.x + X12P.y, X23 = X23P.x + X23P.y;
  float X34 = X34P.x + X34P.y, X78 = X78P.x + X78P.y;
  float vals[21] = {totA, S0,S1,S2,S3,S4,S5,S6,S7,S8, K9,K10,K11,
                    X01,X12,X23,X34,X45,X56,X67,X78};
  wsumB<21>(vals);
  if ((tid & 63) == 0){
    float* A = acc + b*ACCS;
    atomicAdd(A+0, vals[0]);
    #pragma unroll
    for (int p=0;p<12;p++) atomicAdd(A+1+p, vals[1+p]);
    if (t&1) atomicAdd(A+13, vals[0]);
    if (t&2) atomicAdd(A+14, vals[0]);
    if (t&4) atomicAdd(A+15, vals[0]);
    float zz = vals[0] - 2.f*vals[1];
    if (t&8) zz = -zz;
    atomicAdd(A+16, zz);
    #pragma unroll
    for (int j=0;j<8;j++) atomicAdd(A+17+j, vals[13+j]);
  }
}

// ---------------- Tail (unchanged, verified) ----------------
__global__ __launch_bounds__(256) void qs_tail(const float* __restrict__ acc, const float* __restrict__ tryv,
    const float* __restrict__ w1, const float* __restrict__ b1,
    const float* __restrict__ w2, const float* __restrict__ b2,
    const float* __restrict__ g1, const float* __restrict__ be1,
    const float* __restrict__ g2, const float* __restrict__ be2,
    const float* __restrict__ wh, const float* __restrict__ bh,
    float* __restrict__ out){
  int b = blockIdx.x * 256 + threadIdx.x;
  if (b >= BSZQ) return;
  const float* A = acc + b*ACCS;
  float tot = A[0];
  float inv = 1.f / tot;
  float Z[16], X[16];
  Z[0] = A[16] * inv;
  Z[1] = 1.f - 2.f*A[15]*inv;
  Z[2] = 1.f - 2.f*A[14]*inv;
  Z[3] = 1.f - 2.f*A[13]*inv;
  #pragma unroll
  for (int w=4; w<15; w++) Z[w] = 1.f - 2.f*A[1 + (15-w)]*inv;
  Z[15] = 1.f - 2.f*A[1]*inv;
  #pragma unroll
  for (int w=0; w<7; w++) X[w] = A[25+w]*inv;
  #pragma unroll
  for (int w=7; w<15; w++) X[w] = A[16 + (15-w)]*inv;
  X[15] = A[32]*inv;
  float th = tryv[1];
  float ct = cosf(th), st = sinf(th);
  float M4[16];
  #pragma unroll
  for (int w=0; w<16; w++) M4[w] = ct*Z[w] - st*X[w];
  float mu = 0.f;
  #pragma unroll
  for (int w=0; w<16; w++) mu += Z[w];
  mu *= (1.f/16.f);
  float var = 0.f;
  #pragma unroll
  for (int w=0; w<16; w++){ float d = Z[w]-mu; var += d*d; }
  var *= (1.f/16.f);
  float rs = rsqrtf(var + 1e-5f);
  float xln[16];
  #pragma unroll
  for (int w=0; w<16; w++) xln[w] = (Z[w]-mu)*rs*g1[16+w] + be1[16+w];
  float h[64];
  for (int j=0;j<64;j++){
    float sacc = b1[64 + j];
    #pragma unroll
    for (int w=0; w<16; w++) sacc += M4[w] * w1[1024 + j*16 + w];
    h[j] = fmaxf(sacc, 0.f);
  }
  float y[16];
  for (int w=0; w<16; w++){
    float sacc = b2[16 + w];
    #pragma unroll
    for (int j=0;j<64;j++) sacc += h[j] * w2[1024 + w*64 + j];
    y[w] = xln[w] + sacc;
  }
  mu = 0.f;
  #pragma unroll
  for (int w=0; w<16; w++) mu += y[w];
  mu *= (1.f/16.f);
  var = 0.f;
  #pragma unroll
  for (int w=0; w<16; w++){ float d = y[w]-mu; var += d*d; }
  var *= (1.f/16.f);
  rs = rsqrtf(var + 1e-5f);
  float o = bh[0];
  #pragma unroll
  for (int w=0; w<16; w++) o += ((y[w]-mu)*rs*g2[16+w] + be2[16+w]) * wh[w];
  out[b] = o;
}

extern "C" void kernel_launch(void* const* d_in, const int* in_sizes, int n_in,
                              void* d_out, int out_size, void* d_ws, size_t ws_size,
                              hipStream_t stream) {
  const float* states = (const float*)d_in[0];
  const float* ra     = (const float*)d_in[1];
  const float* trx    = (const float*)d_in[2];
  const float* tryv   = (const float*)d_in[3];
  const float* w1     = (const float*)d_in[4];
  const float* b1     = (const float*)d_in[5];
  const float* w2     = (const float*)d_in[6];
  const float* b2     = (const float*)d_in[7];
  const float* g1     = (const float*)d_in[8];
  const float* be1    = (const float*)d_in[9];
  const float* g2     = (const float*)d_in[10];
  const float* be2    = (const float*)d_in[11];
  const float* wh     = (const float*)d_in[12];
  const float* bh     = (const float*)d_in[13];
  float* out = (float*)d_out;

  unsigned int* psi = (unsigned int*)d_ws;                                 // 128 MiB (fp16 amps)
  float* acc  = (float*)((char*)d_ws + (size_t)BSZQ*65536*sizeof(float2)); // keep old offset (512 x 40)
  float* gt = out;  // gate table in d_out scratch; qs_tail overwrites it all

  dim3 g(BSZQ*16);
  qs_prep<<<1, 64, 0, stream>>>(ra, trx, tryv, gt);
  qs_p1<<<g, NT, 0, stream>>>(states, gt, psi, acc);
  qs_p2<<<g, NT, 0, stream>>>(psi, gt);
  qs_p4<<<g, NT, 0, stream>>>(psi, gt, acc);
  qs_p5<<<g, NT, 0, stream>>>(psi, gt, acc);
  qs_tail<<<2, 256, 0, stream>>>(acc, tryv, w1, b1, w2, b2, g1, be1, g2, be2, wh, bh, out);
}

// Round 9
// 517.479 us; speedup vs baseline: 1.0421x; 1.0354x over previous
//
#include <hip/hip_runtime.h>
#include <math.h>

// 16-qubit statevector, 512 batch. psi FP16 (half2/amp), 128 MiB.
// This round: PACKED-FP16 ARITHMETIC in p2/p4/p5 (p1 stays fp32).
//  * v_pk_fma_f16 (32-bit VOP3P, 2cy) replaces v_pk_fma_f32 (64-bit, 4cy):
//    2x issue rate on the dominant butterfly stream.
//  * All measures accumulate fp32 via v_dot2_f32_f16 (f16 products exact in
//    fp32): dots, |amp|^2 class sums.
//  * Amps live as one u32 (f16x2) per amp: loads/stores are raw u32 (all
//    h2f/f2h cvts deleted); cross-lane swizzles/dpp halve (1 per amp).
//  * LDS transposes revert to single-round round-6 structure with u32
//    elements (16 KB), universal swizzle SWB = i^((i>>8)&15)^(((i>>8)&1)<<4)
//    -> 2-way (free) bank access on both sides of every exchange.
// Index algebra and measurement formulas identical to the verified scheme.

#define NT 256
#define ACCS 40
#define BSZQ 512

typedef float v2f __attribute__((ext_vector_type(2)));
typedef __fp16 h2t __attribute__((ext_vector_type(2)));

__device__ __forceinline__ v2f mk2(float a, float b){ v2f r; r.x = a; r.y = b; return r; }

__device__ __forceinline__ void wave_fence(){
  asm volatile("" ::: "memory");
  __builtin_amdgcn_wave_barrier();
  asm volatile("" ::: "memory");
}

__device__ __forceinline__ unsigned f2h(v2f a){
  h2t h = __builtin_amdgcn_cvt_pkrtz(a.x, a.y);
  return *(unsigned*)&h;
}

// ---- packed fp32 primitives (p1 only) ----
__device__ __forceinline__ v2f pk_mul(v2f a, v2f b){
  v2f d; asm("v_pk_mul_f32 %0, %1, %2" : "=v"(d) : "v"(a), "v"(b)); return d;
}
__device__ __forceinline__ void pk_fma_acc(v2f& c, v2f a, v2f b){
  asm("v_pk_fma_f32 %0, %1, %2, %0" : "+v"(c) : "v"(a), "v"(b));
}
__device__ __forceinline__ void pk_fma_sw_acc(v2f& c, v2f a, v2f b){
  asm("v_pk_fma_f32 %0, %1, %2, %0 op_sel:[1,0,0] op_sel_hi:[0,1,1]"
      : "+v"(c) : "v"(a), "v"(b));
}

// ---- packed fp16 primitives (p2/p4/p5) ----
__device__ __forceinline__ unsigned pk16_mul(unsigned a, unsigned b){
  unsigned d; asm("v_pk_mul_f16 %0, %1, %2" : "=v"(d) : "v"(a), "v"(b)); return d;
}
__device__ __forceinline__ void pk16_fma_acc(unsigned& c, unsigned a, unsigned b){
  asm("v_pk_fma_f16 %0, %1, %2, %0" : "+v"(c) : "v"(a), "v"(b));
}
__device__ __forceinline__ void pk16_fma_sw_acc(unsigned& c, unsigned a, unsigned b){
  asm("v_pk_fma_f16 %0, %1, %2, %0 op_sel:[1,0,0] op_sel_hi:[0,1,1]"
      : "+v"(c) : "v"(a), "v"(b));
}
// fp32 accumulate of f16-pair dot: s += a.lo*b.lo + a.hi*b.hi (exact products)
__device__ __forceinline__ void dot2acc(float& s, unsigned a, unsigned b){
  asm("v_dot2_f32_f16 %0, %1, %2, %0" : "+v"(s) : "v"(a), "v"(b));
}

struct C2 { float r, i; };
struct G1Q { C2 a, b, c, d; };

__device__ __forceinline__ C2 cmul(C2 x, C2 y){ return C2{ x.r*y.r - x.i*y.i, x.r*y.i + x.i*y.r }; }
__device__ __forceinline__ C2 cadd(C2 x, C2 y){ return C2{ x.r + y.r, x.i + y.i }; }
__device__ __forceinline__ G1Q mkRX(float th){
  float cc = cosf(0.5f*th), ss = sinf(0.5f*th);
  return G1Q{ C2{cc,0.f}, C2{0.f,-ss}, C2{0.f,-ss}, C2{cc,0.f} };
}
__device__ __forceinline__ G1Q mkRY(float th){
  float cc = cosf(0.5f*th), ss = sinf(0.5f*th);
  return G1Q{ C2{cc,0.f}, C2{-ss,0.f}, C2{ss,0.f}, C2{cc,0.f} };
}
__device__ __forceinline__ G1Q gmul(G1Q A, G1Q B){
  return G1Q{ cadd(cmul(A.a,B.a), cmul(A.b,B.c)),
              cadd(cmul(A.a,B.b), cmul(A.b,B.d)),
              cadd(cmul(A.c,B.a), cmul(A.d,B.c)),
              cadd(cmul(A.c,B.b), cmul(A.d,B.d)) };
}

struct PG1Q { v2f aR, aI, bR, bI, cR, cI, dR, dI; };
__device__ __forceinline__ PG1Q loadPG(const float* __restrict__ gt, int i){
  const float4* p = (const float4*)(gt + i*8);
  float4 u = p[0], w = p[1];
  PG1Q g;
  g.aR = mk2(u.x, u.x); g.aI = mk2(-u.y, u.y);
  g.bR = mk2(u.z, u.z); g.bI = mk2(-u.w, u.w);
  g.cR = mk2(w.x, w.x); g.cI = mk2(-w.y, w.y);
  g.dR = mk2(w.z, w.z); g.dI = mk2(-w.w, w.w);
  return g;
}
// f16 gate: 8 u32s at float-offset 112 + i*8 of the table.
struct PGH { unsigned aR, aI, bR, bI, cR, cI, dR, dI; };
__device__ __forceinline__ PGH loadPGH(const float* __restrict__ gt, int i){
  const uint4* p = (const uint4*)((const unsigned*)gt + 112 + i*8);
  uint4 u = p[0], w = p[1];
  return PGH{u.x, u.y, u.z, u.w, w.x, w.y, w.z, w.w};
}
__device__ __forceinline__ unsigned pkh(float lo, float hi){
  __fp16 l = (__fp16)lo, h = (__fp16)hi;   // RNE for coeffs
  unsigned short lb, hb;
  __builtin_memcpy(&lb, &l, 2); __builtin_memcpy(&hb, &h, 2);
  return (unsigned)lb | ((unsigned)hb<<16);
}

// p1 16KB two-round transpose swizzle (v2f elements) — unchanged from r8.
__device__ __forceinline__ int SW(int i){ return (i & ~15) | ((i ^ (i>>4) ^ (i>>8)) & 15); }
// Universal u32-transpose swizzle: 2-way banks on both sides of each exchange.
__device__ __forceinline__ int SWB(int i){ return i ^ ((i>>8)&15) ^ (((i>>8)&1)<<4); }

template<int M>
__device__ __forceinline__ float swzx(float x){
  return __int_as_float(__builtin_amdgcn_ds_swizzle(__float_as_int(x), (M<<10)|0x1F));
}
template<int M>
__device__ __forceinline__ unsigned swzu(unsigned x){
  return (unsigned)__builtin_amdgcn_ds_swizzle((int)x, (M<<10)|0x1F);
}
template<int C>
__device__ __forceinline__ unsigned dppu(unsigned x){
  return (unsigned)__builtin_amdgcn_mov_dpp((int)x, C, 0xF, 0xF, true);
}
template<int C>
__device__ __forceinline__ float dppx(float x){
  return __int_as_float(__builtin_amdgcn_mov_dpp(__float_as_int(x), C, 0xF, 0xF, true));
}
// Stage-major batched full-wave sums.
template<int N>
__device__ __forceinline__ void wsumB(float* x){
  #pragma unroll
  for (int i=0;i<N;i++) x[i] += dppx<0xB1>(x[i]);
  #pragma unroll
  for (int i=0;i<N;i++) x[i] += dppx<0x4E>(x[i]);
  #pragma unroll
  for (int i=0;i<N;i++) x[i] += swzx<4>(x[i]);
  #pragma unroll
  for (int i=0;i<N;i++) x[i] += swzx<8>(x[i]);
  #pragma unroll
  for (int i=0;i<N;i++) x[i] += swzx<16>(x[i]);
  #pragma unroll
  for (int i=0;i<N;i++)
    x[i] = __int_as_float(__builtin_amdgcn_readlane(__float_as_int(x[i]), 0)) +
           __int_as_float(__builtin_amdgcn_readlane(__float_as_int(x[i]), 32));
}

// fp32 butterfly (p1)
__device__ __forceinline__ void greg16p(v2f* v, const PG1Q g, const int q){
  const int bq = 1<<q;
  #pragma unroll
  for (int r=0;r<16;r++){
    if (r & bq) continue;
    v2f a0 = v[r], a1 = v[r|bq];
    v2f t0 = pk_mul(a0, g.aR);
    pk_fma_sw_acc(t0, a0, g.aI);
    pk_fma_acc   (t0, a1, g.bR);
    pk_fma_sw_acc(t0, a1, g.bI);
    v2f t1 = pk_mul(a0, g.cR);
    pk_fma_sw_acc(t1, a0, g.cI);
    pk_fma_acc   (t1, a1, g.dR);
    pk_fma_sw_acc(t1, a1, g.dI);
    v[r] = t0; v[r|bq] = t1;
  }
}
// fp16 butterfly (p2/p4/p5): 8 pk16 ops per pair at 2cy each.
__device__ __forceinline__ void greg16h(unsigned* v, const PGH g, const int q){
  const int bq = 1<<q;
  #pragma unroll
  for (int r=0;r<16;r++){
    if (r & bq) continue;
    unsigned a0 = v[r], a1 = v[r|bq];
    unsigned t0 = pk16_mul(a0, g.aR);
    pk16_fma_sw_acc(t0, a0, g.aI);
    pk16_fma_acc   (t0, a1, g.bR);
    pk16_fma_sw_acc(t0, a1, g.bI);
    unsigned t1 = pk16_mul(a0, g.cR);
    pk16_fma_sw_acc(t1, a0, g.cI);
    pk16_fma_acc   (t1, a1, g.dR);
    pk16_fma_sw_acc(t1, a1, g.dI);
    v[r] = t0; v[r|bq] = t1;
  }
}
__device__ __forceinline__ void creg16(v2f* v, const int qc, const int qt){
  #pragma unroll
  for (int r=0;r<16;r++){
    if ((r & (1<<qc)) && !(r & (1<<qt))){
      v2f tmp = v[r]; v[r] = v[r|(1<<qt)]; v[r|(1<<qt)] = tmp;
    }
  }
}
__device__ __forceinline__ void creg16u(unsigned* v, const int qc, const int qt){
  #pragma unroll
  for (int r=0;r<16;r++){
    if ((r & (1<<qc)) && !(r & (1<<qt))){
      unsigned tmp = v[r]; v[r] = v[r|(1<<qt)]; v[r|(1<<qt)] = tmp;
    }
  }
}
__device__ __forceinline__ float xdot16h(const unsigned* v, const int m){
  float s = 0.f;
  #pragma unroll
  for (int r=0;r<16;r++) dot2acc(s, v[r], v[r^m]);
  return s;
}

// ---------------- P0: bake gates (fp32 table + fp16 table) ----------------
__global__ void qs_prep(const float* __restrict__ ra, const float* __restrict__ trx,
                        const float* __restrict__ tryv, float* __restrict__ gt){
  if (threadIdx.x != 0) return;
  float trx0 = trx[0];
  G1Q RX0 = mkRX(trx0);
  G1Q g[14];
  g[0]  = gmul(RX0, gmul(mkRY(ra[19]), mkRX(ra[3])));   // p1 alpha q0 (w15)
  g[1]  = mkRX(trx0 + ra[6]);                           // p1 alpha q1
  g[2]  = mkRX(trx0 + ra[9]);                           // p1 alpha q2
  g[3]  = mkRX(trx0 + ra[12]);                          // p1 alpha q3
  g[4]  = mkRX(trx0 + ra[15]);                          // p1 beta q0
  g[5]  = mkRX(trx0 + ra[18]);                          // p1 beta q1
  g[6]  = RX0;                                          // shared
  g[7]  = gmul(RX0, mkRY(ra[4]));                       // p2 A q3 (w4)
  g[8]  = mkRY(ra[1]);                                  // p2 A q2 (w5 RY)
  g[9]  = gmul(RX0, mkRY(ra[7]));                       // p2 B q0 (w3)
  g[10] = gmul(RX0, mkRY(ra[10]));                      // p2 B q1 (w2)
  g[11] = gmul(RX0, mkRY(ra[13]));                      // p2 B q2 (w1)
  g[12] = gmul(RX0, gmul(mkRY(ra[16]), mkRX(ra[0])));   // p2 B q3 (w0)
  g[13] = gmul(mkRX(trx[1]), mkRY(tryv[0]));            // U for p4/p5
  for (int i=0;i<14;i++){
    gt[i*8+0]=g[i].a.r; gt[i*8+1]=g[i].a.i;
    gt[i*8+2]=g[i].b.r; gt[i*8+3]=g[i].b.i;
    gt[i*8+4]=g[i].c.r; gt[i*8+5]=g[i].c.i;
    gt[i*8+6]=g[i].d.r; gt[i*8+7]=g[i].d.i;
  }
  unsigned* gh = (unsigned*)gt + 112;
  for (int i=0;i<14;i++){
    gh[i*8+0] = pkh( g[i].a.r,  g[i].a.r);
    gh[i*8+1] = pkh(-g[i].a.i,  g[i].a.i);
    gh[i*8+2] = pkh( g[i].b.r,  g[i].b.r);
    gh[i*8+3] = pkh(-g[i].b.i,  g[i].b.i);
    gh[i*8+4] = pkh( g[i].c.r,  g[i].c.r);
    gh[i*8+5] = pkh(-g[i].c.i,  g[i].c.i);
    gh[i*8+6] = pkh( g[i].d.r,  g[i].d.r);
    gh[i*8+7] = pkh(-g[i].d.i,  g[i].d.i);
  }
}

// ---------------- P1 (L tile, fp32 math — unchanged from round 8) ----------------
__global__ __launch_bounds__(NT) void qs_p1(const float* __restrict__ x, const float* __restrict__ gt,
                                            unsigned* __restrict__ psi, float* __restrict__ acc){
  __shared__ __align__(16) v2f s[2048];
  int b = blockIdx.x >> 4, t = blockIdx.x & 15;
  int tid = threadIdx.x;
  if (t == 0 && tid < ACCS) acc[b*ACCS + tid] = 0.f;
  v2f v[16];
  const float4* xb = (const float4*)(x + (size_t)b*65536 + t*4096 + tid*16);
  #pragma unroll
  for (int q=0;q<4;q++){
    float4 f = xb[q];
    v[4*q+0] = mk2(f.x, 0.f);
    v[4*q+1] = mk2(f.y, 0.f);
    v[4*q+2] = mk2(f.z, 0.f);
    v[4*q+3] = mk2(f.w, 0.f);
  }
  greg16p(v, loadPG(gt,0), 0);   // w15
  greg16p(v, loadPG(gt,1), 1);   // w14
  greg16p(v, loadPG(gt,2), 2);   // w13
  greg16p(v, loadPG(gt,3), 3);   // w12
  // two-round intra-wave transpose (alpha -> beta frame)
  {
    int wbase = ((tid&15)<<3) | ((tid>>4)<<7);
    int rbase = (tid&7) | ((tid>>4)<<7);
    v2f tmp[8];
    #pragma unroll
    for (int j=0;j<8;j++) s[SW(j | wbase)] = v[j];
    wave_fence();
    if (!(tid & 8)){
      #pragma unroll
      for (int r=0;r<8;r++)  v[r]     = s[SW(rbase | (r<<3))];
      #pragma unroll
      for (int r=8;r<16;r++) tmp[r-8] = s[SW(rbase | (r<<3))];
    }
    wave_fence();
    #pragma unroll
    for (int j=8;j<16;j++) s[SW((j&7) | wbase)] = v[j];
    wave_fence();
    if (tid & 8){
      #pragma unroll
      for (int r=0;r<16;r++) v[r] = s[SW(rbase | (r<<3))];
    } else {
      #pragma unroll
      for (int r=8;r<16;r++) v[r] = tmp[r-8];
    }
  }
  creg16(v, 1, 0);                       // C(w10->w11)
  creg16(v, 2, 1);                       // C(w9->w10)
  creg16(v, 3, 2);                       // C(w8->w9)
  {                                      // C(w7->w8)
    bool c8 = (tid & 16);
    #pragma unroll
    for (int r=0;r<8;r++){
      v2f lo = v[r], hi = v[r|8];
      v[r]   = c8 ? hi : lo;
      v[r|8] = c8 ? lo : hi;
    }
  }
  greg16p(v, loadPG(gt,4), 0);   // w11
  greg16p(v, loadPG(gt,5), 1);   // w10
  PG1Q PG6 = loadPG(gt,6);
  greg16p(v, PG6, 2);            // w9
  greg16p(v, PG6, 3);            // w8
  unsigned* pbL = psi + (size_t)b*65536 + t*4096;
  #pragma unroll
  for (int r=0;r<16;r++) pbL[(tid&15) | (r<<4) | ((tid>>4)<<8)] = f2h(v[r]);
}

// ---------------- P2 (H tile, fp16 math, single-round u32 transpose) ----------------
__global__ __launch_bounds__(NT) void qs_p2(unsigned* __restrict__ psi, const float* __restrict__ gt){
  __shared__ unsigned s[4096];   // 16 KB
  int b = blockIdx.x >> 4, t = blockIdx.x & 15;
  int tid = threadIdx.x;
  int a = tid & 15, g = tid >> 4;
  unsigned v[16];
  unsigned* pb = psi + (size_t)b*65536;
  #pragma unroll
  for (int r=0;r<16;r++)
    v[r] = pb[a | (t<<4) | (r<<8) | (g<<12)];
  greg16h(v, loadPGH(gt,7), 3);   // w4
  greg16h(v, loadPGH(gt,8), 2);   // w5 (RY part)
  creg16u(v, 1, 0);               // C(w6->w7)
  creg16u(v, 2, 1);               // C(w5->w6)
  PGH G6 = loadPGH(gt,6);
  greg16h(v, G6, 2);              // w5
  greg16h(v, G6, 1);              // w6
  greg16h(v, G6, 0);              // w7
  // single-round transpose: v_new[r](a,g) = v_old[g] of thread (a,r)
  #pragma unroll
  for (int r=0;r<16;r++) s[SWB(a | (g<<4) | (r<<8))] = v[r];
  __syncthreads();
  #pragma unroll
  for (int r=0;r<16;r++) v[r] = s[SWB(a | (r<<4) | (g<<8))];
  greg16h(v, loadPGH(gt,9), 0);    // w3
  greg16h(v, loadPGH(gt,10), 1);   // w2
  greg16h(v, loadPGH(gt,11), 2);   // w1
  greg16h(v, loadPGH(gt,12), 3);   // w0
  #pragma unroll
  for (int r=0;r<16;r++)
    pb[a | (t<<4) | (g<<8) | (r<<12)] = v[r];
}

// ---------------- P4 (H tile on y-frame, fp16 math) ----------------
// Phases A (y0..3) -> C (y12..15) -> B (y8..11). A->C intra-wave (fences);
// C->B inter-wave (1 barrier). Single-round u32 transposes, SWB swizzle.
__global__ __launch_bounds__(NT) void qs_p4(unsigned* __restrict__ psi, const float* __restrict__ gt,
                                            float* __restrict__ acc){
  __shared__ unsigned s[4096];   // 16 KB
  int b = blockIdx.x >> 4, t = blockIdx.x & 15;
  int tid = threadIdx.x;
  PGH U = loadPGH(gt, 13);
  unsigned* pb = psi + (size_t)b*65536;
  unsigned v[16];
  // ---- phase A: regs y0..3; tid: b0..3 = y12..15, b4..7 = y8..11 ----
  {
    int Y = (tid>>4) | ((tid&15)<<4);          // y8..15
    int XH = Y ^ (Y>>1);                       // x8..15
    int x7 = ((t>>3) ^ Y) & 1;                 // t3 ^ y8
    int runbase = (XH<<8) | (x7<<7) | (((t ^ (t>>1)) & 7) << 4);
    const uint4* rp = (const uint4*)(pb + runbase);
    unsigned tmp[16];
    #pragma unroll
    for (int q=0;q<4;q++){
      uint4 u = rp[q];
      tmp[4*q+0] = u.x;
      tmp[4*q+1] = u.y;
      tmp[4*q+2] = u.z;
      tmp[4*q+3] = u.w;
    }
    if (t & 1){
      v[15]=tmp[0];  v[14]=tmp[1];  v[12]=tmp[2];  v[13]=tmp[3];
      v[ 8]=tmp[4];  v[ 9]=tmp[5];  v[11]=tmp[6];  v[10]=tmp[7];
      v[ 0]=tmp[8];  v[ 1]=tmp[9];  v[ 3]=tmp[10]; v[ 2]=tmp[11];
      v[ 7]=tmp[12]; v[ 6]=tmp[13]; v[ 4]=tmp[14]; v[ 5]=tmp[15];
    } else {
      v[ 0]=tmp[0];  v[ 1]=tmp[1];  v[ 3]=tmp[2];  v[ 2]=tmp[3];
      v[ 7]=tmp[4];  v[ 6]=tmp[5];  v[ 4]=tmp[6];  v[ 5]=tmp[7];
      v[15]=tmp[8];  v[14]=tmp[9];  v[12]=tmp[10]; v[13]=tmp[11];
      v[ 8]=tmp[12]; v[ 9]=tmp[13]; v[11]=tmp[14]; v[10]=tmp[15];
    }
    // K = C(w15->w0): ctrl y0 (reg bit0), tgt y15 (lane bit3) -> one u32 swizzle
    #pragma unroll
    for (int r=1;r<16;r+=2) v[r] = swzu<8>(v[r]);
    greg16h(v, U, 0); greg16h(v, U, 1); greg16h(v, U, 2); greg16h(v, U, 3); // w15..w12
    // A->C write: slot = j | (g<<4) | (q<<8)
    #pragma unroll
    for (int j=0;j<16;j++)
      s[SWB(j | ((tid>>4)<<4) | ((tid&15)<<8))] = v[j];
  }
  wave_fence();   // A->C intra-wave (partners share tid>>4)
  float Xa, Xb, Xc, Xd;
  // ---- phase C: regs y12..15; tid: b0..3 = y0..3, b4..7 = y8..11 ----
  {
    #pragma unroll
    for (int r=0;r<16;r++)
      v[r] = s[SWB((tid&15) | ((tid>>4)<<4) | (r<<8))];
    greg16h(v, U, 0); greg16h(v, U, 1); greg16h(v, U, 2); greg16h(v, U, 3); // w3..w0
    creg16u(v, 3, 2);  // chain1 C(w0->w1)
    creg16u(v, 2, 1);  // C(w1->w2)
    creg16u(v, 1, 0);  // C(w2->w3)
    Xa = xdot16h(v, 8);   // X_w0 (y15)
    Xb = xdot16h(v, 4);   // X_w1 (y14)
    Xc = xdot16h(v, 2);   // X_w2 (y13)
    Xd = 0.f;             // <X_w0 X_w15>: reg^8 x lane-xor1 (DPP)
    #pragma unroll
    for (int r=0;r<16;r++) dot2acc(Xd, v[r], dppu<0xB1>(v[r^8]));
    wave_fence();   // each thread overwrites exactly the slots it read
    #pragma unroll
    for (int r=0;r<16;r++)
      s[SWB((tid&15) | ((tid>>4)<<4) | (r<<8))] = v[r];
  }
  __syncthreads();  // C->B is inter-wave: the one required barrier
  // ---- phase B: regs y8..11; tid: b0..3 = y0..3, b4..7 = y12..15 ----
  float Xe, Xf, Xg, Xh;
  {
    #pragma unroll
    for (int r=0;r<16;r++)
      v[r] = s[SWB((tid&15) | (r<<4) | ((tid>>4)<<8))];
    greg16h(v, U, 0); greg16h(v, U, 1); greg16h(v, U, 2); greg16h(v, U, 3); // w7..w4
    {                                  // C(w3->w4): ctrl y12 = tid bit4, tgt y11 = r3
      bool c12 = (tid & 16);
      #pragma unroll
      for (int r=0;r<8;r++){
        unsigned lo = v[r], hi = v[r|8];
        v[r]   = c12 ? hi : lo;
        v[r|8] = c12 ? lo : hi;
      }
    }
    creg16u(v, 3, 2);  // C(w4->w5)
    creg16u(v, 2, 1);  // C(w5->w6)
    creg16u(v, 1, 0);  // C(w6->w7)
    Xe = 0.f;          // X_w3 (y12 = lane bit4)
    #pragma unroll
    for (int r=0;r<16;r++) dot2acc(Xe, v[r], swzu<16>(v[r]));
    Xf = xdot16h(v, 8);   // X_w4
    Xg = xdot16h(v, 4);   // X_w5
    Xh = xdot16h(v, 2);   // X_w6
    int Bs = (tid&15) | (t<<4) | ((tid>>4)<<12);
    int Cs = Bs ^ (Bs>>1);
    #pragma unroll
    for (int r=0;r<16;r++)
      pb[Cs ^ ((r<<8) ^ (r<<7))] = v[r];
  }
  float vals[8] = {Xa, Xb, Xc, Xe, Xf, Xg, Xh, Xd};
  wsumB<8>(vals);
  if ((tid & 63) == 0){
    float* A = acc + b*ACCS;
    #pragma unroll
    for (int i=0;i<7;i++) atomicAdd(A+25+i, vals[i]);
    atomicAdd(A+32, vals[7]);
  }
}

// ---------------- P5 (L tile, read-only, fp16 math, no LDS) ----------------
__global__ __launch_bounds__(NT) void qs_p5(const unsigned* __restrict__ psi, const float* __restrict__ gt,
                                            float* __restrict__ acc){
  int b = blockIdx.x >> 4, t = blockIdx.x & 15;
  int tid = threadIdx.x;
  PGH U = loadPGH(gt, 13);
  const unsigned* pb = psi + (size_t)b*65536;
  unsigned v[16];
  int Bv = (t<<12) | ((tid>>4)<<8) | (tid&15);
  int Cg = Bv ^ (Bv>>1);
  #pragma unroll
  for (int r=0;r<16;r++)
    v[r] = pb[Cg ^ ((r<<4) ^ (r<<3))];
  greg16h(v, U, 0); greg16h(v, U, 1); greg16h(v, U, 2); greg16h(v, U, 3); // w11..w8
  float totA=0.f, S4l=0.f, S5l=0.f, S6l=0.f, S7l=0.f;
  #pragma unroll
  for (int r=0;r<16;r++){
    dot2acc(totA, v[r], v[r]);
    if (__popc(r)&1)    dot2acc(S4l, v[r], v[r]);
    if (__popc(r>>1)&1) dot2acc(S5l, v[r], v[r]);
    if (__popc(r>>2)&1) dot2acc(S6l, v[r], v[r]);
    if (__popc(r>>3)&1) dot2acc(S7l, v[r], v[r]);
  }
  float S4h = totA - S4l;
  float S0 = (__popc(tid & 0x1F)&1) ? S4h : S4l;   // parity(ul0..8)
  float S1 = (__popc(tid & 0x1E)&1) ? S4h : S4l;   // parity(ul1..8)
  float S2 = (__popc(tid & 0x1C)&1) ? S4h : S4l;   // parity(ul2..8)
  float S3 = (__popc(tid & 0x18)&1) ? S4h : S4l;   // parity(ul3..8)
  bool u8 = (tid & 16);
  float S4 = u8 ? S4h : S4l;                       // parity(ul4..8)
  float S5 = u8 ? totA - S5l : S5l;
  float S6 = u8 ? totA - S6l : S6l;
  float S7 = u8 ? totA - S7l : S7l;
  float S8 = u8 ? totA : 0.f;
  float K9  = (tid & 32) ? totA : 0.f;
  float K10 = (tid & 64) ? totA : 0.f;
  float K11 = (tid & 128)? totA : 0.f;
  float X45 = xdot16h(v,3), X56 = xdot16h(v,6), X67 = xdot16h(v,12);
  float X01=0.f, X12=0.f, X23=0.f, X34=0.f, X78=0.f;
  #pragma unroll
  for (int r=0;r<16;r++){
    dot2acc(X01, v[r], dppu<0x1B>(v[r]));     // lane xor3 (ul0,ul1)
    dot2acc(X12, v[r], swzu<6>(v[r]));        // lane xor6 (ul1,ul2)
    dot2acc(X23, v[r], swzu<12>(v[r]));       // lane xor12 (ul2,ul3)
    dot2acc(X34, v[r], swzu<8>(v[r^1]));      // ul3 x ul4
    dot2acc(X78, v[r], swzu<16>(v[r^8]));     // ul7 x ul8
  }
  float vals[21] = {totA, S0,S1,S2,S3,S4,S5,S6,S7,S8, K9,K10,K11,
                    X01,X12,X23,X34,X45,X56,X67,X78};
  wsumB<21>(vals);
  if ((tid & 63) == 0){
    float* A = acc + b*ACCS;
    atomicAdd(A+0, vals[0]);
    #pragma unroll
    for (int p=0;p<12;p++) atomicAdd(A+1+p, vals[1+p]);
    if (t&1) atomicAdd(A+13, vals[0]);
    if (t&2) atomicAdd(A+14, vals[0]);
    if (t&4) atomicAdd(A+15, vals[0]);
    float zz = vals[0] - 2.f*vals[1];
    if (t&8) zz = -zz;
    atomicAdd(A+16, zz);
    #pragma unroll
    for (int j=0;j<8;j++) atomicAdd(A+17+j, vals[13+j]);
  }
}

// ---------------- Tail (unchanged, verified) ----------------
__global__ __launch_bounds__(256) void qs_tail(const float* __restrict__ acc, const float* __restrict__ tryv,
    const float* __restrict__ w1, const float* __restrict__ b1,
    const float* __restrict__ w2, const float* __restrict__ b2,
    const float* __restrict__ g1, const float* __restrict__ be1,
    const float* __restrict__ g2, const float* __restrict__ be2,
    const float* __restrict__ wh, const float* __restrict__ bh,
    float* __restrict__ out){
  int b = blockIdx.x * 256 + threadIdx.x;
  if (b >= BSZQ) return;
  const float* A = acc + b*ACCS;
  float tot = A[0];
  float inv = 1.f / tot;
  float Z[16], X[16];
  Z[0] = A[16] * inv;
  Z[1] = 1.f - 2.f*A[15]*inv;
  Z[2] = 1.f - 2.f*A[14]*inv;
  Z[3] = 1.f - 2.f*A[13]*inv;
  #pragma unroll
  for (int w=4; w<15; w++) Z[w] = 1.f - 2.f*A[1 + (15-w)]*inv;
  Z[15] = 1.f - 2.f*A[1]*inv;
  #pragma unroll
  for (int w=0; w<7; w++) X[w] = A[25+w]*inv;
  #pragma unroll
  for (int w=7; w<15; w++) X[w] = A[16 + (15-w)]*inv;
  X[15] = A[32]*inv;
  float th = tryv[1];
  float ct = cosf(th), st = sinf(th);
  float M4[16];
  #pragma unroll
  for (int w=0; w<16; w++) M4[w] = ct*Z[w] - st*X[w];
  float mu = 0.f;
  #pragma unroll
  for (int w=0; w<16; w++) mu += Z[w];
  mu *= (1.f/16.f);
  float var = 0.f;
  #pragma unroll
  for (int w=0; w<16; w++){ float d = Z[w]-mu; var += d*d; }
  var *= (1.f/16.f);
  float rs = rsqrtf(var + 1e-5f);
  float xln[16];
  #pragma unroll
  for (int w=0; w<16; w++) xln[w] = (Z[w]-mu)*rs*g1[16+w] + be1[16+w];
  float h[64];
  for (int j=0;j<64;j++){
    float sacc = b1[64 + j];
    #pragma unroll
    for (int w=0; w<16; w++) sacc += M4[w] * w1[1024 + j*16 + w];
    h[j] = fmaxf(sacc, 0.f);
  }
  float y[16];
  for (int w=0; w<16; w++){
    float sacc = b2[16 + w];
    #pragma unroll
    for (int j=0;j<64;j++) sacc += h[j] * w2[1024 + w*64 + j];
    y[w] = xln[w] + sacc;
  }
  mu = 0.f;
  #pragma unroll
  for (int w=0; w<16; w++) mu += y[w];
  mu *= (1.f/16.f);
  var = 0.f;
  #pragma unroll
  for (int w=0; w<16; w++){ float d = y[w]-mu; var += d*d; }
  var *= (1.f/16.f);
  rs = rsqrtf(var + 1e-5f);
  float o = bh[0];
  #pragma unroll
  for (int w=0; w<16; w++) o += ((y[w]-mu)*rs*g2[16+w] + be2[16+w]) * wh[w];
  out[b] = o;
}

extern "C" void kernel_launch(void* const* d_in, const int* in_sizes, int n_in,
                              void* d_out, int out_size, void* d_ws, size_t ws_size,
                              hipStream_t stream) {
  const float* states = (const float*)d_in[0];
  const float* ra     = (const float*)d_in[1];
  const float* trx    = (const float*)d_in[2];
  const float* tryv   = (const float*)d_in[3];
  const float* w1     = (const float*)d_in[4];
  const float* b1     = (const float*)d_in[5];
  const float* w2     = (const float*)d_in[6];
  const float* b2     = (const float*)d_in[7];
  const float* g1     = (const float*)d_in[8];
  const float* be1    = (const float*)d_in[9];
  const float* g2     = (const float*)d_in[10];
  const float* be2    = (const float*)d_in[11];
  const float* wh     = (const float*)d_in[12];
  const float* bh     = (const float*)d_in[13];
  float* out = (float*)d_out;

  unsigned* psi = (unsigned*)d_ws;                                         // 128 MiB (fp16 amps)
  float* acc  = (float*)((char*)d_ws + (size_t)BSZQ*65536*sizeof(float2)); // keep old offset (512 x 40)
  float* gt = out;  // gate tables (112 f32 + 112 u32 = 896B of 2048B); qs_tail overwrites all

  dim3 g(BSZQ*16);
  qs_prep<<<1, 64, 0, stream>>>(ra, trx, tryv, gt);
  qs_p1<<<g, NT, 0, stream>>>(states, gt, psi, acc);
  qs_p2<<<g, NT, 0, stream>>>(psi, gt);
  qs_p4<<<g, NT, 0, stream>>>(psi, gt, acc);
  qs_p5<<<g, NT, 0, stream>>>(psi, gt, acc);
  qs_tail<<<2, 256, 0, stream>>>(acc, tryv, w1, b1, w2, b2, g1, be1, g2, be2, wh, bh, out);
}